// Round 2
// baseline (12301.499 us; speedup 1.0000x reference)
//
#include <hip/hip_runtime.h>
#include <hip/hip_bf16.h>
#include <math.h>

#define NN 100000
#define NE 3200000
#define FIN 128
#define HD 64
#define NL 64
#define NC 47
#define RPW 4               // rows per wave
#define WPB 4               // waves per block
#define RPB (RPW * WPB)     // rows per block = 16

#define SEGSH 13            // source segment = 8192 nodes (1 MiB of bf16 g)
#define NSEG 13             // ceil(100000 / 8192)
#define NKEY (NN * NSEG)    // 1.3M (dst, seg) keys
#define KB ((NKEY + 1023) / 1024)   // scan blocks

// ---------------- helpers ----------------

__device__ __forceinline__ float bf2f(unsigned short u) {
    union { unsigned int i; float f; } v; v.i = ((unsigned int)u) << 16; return v.f;
}
__device__ __forceinline__ unsigned short f2bf(float f) {
    __hip_bfloat16 h = __float2bfloat16(f);   // RNE
    return *reinterpret_cast<unsigned short*>(&h);
}
__device__ __forceinline__ float bflo(unsigned int u) {
    union { unsigned int i; float f; } v; v.i = u << 16; return v.f;
}
__device__ __forceinline__ float bfhi(unsigned int u) {
    union { unsigned int i; float f; } v; v.i = u & 0xFFFF0000u; return v.f;
}
__device__ __forceinline__ float fin_at(const void* p, int isf32, size_t i) {
    return isf32 ? ((const float*)p)[i]
                 : __bfloat162float(((const __hip_bfloat16*)p)[i]);
}
__device__ __forceinline__ int edge_at(const void* p, int is64, size_t i) {
    return is64 ? (int)((const long long*)p)[i] : ((const int*)p)[i];
}

// pair gather: lanes 0-31 read edge ca's row, lanes 32-63 read edge cb's row.
// each lane reads dword (lane&31) of its row = columns {2m, 2m+1}.
__device__ __forceinline__ unsigned int gpair(const unsigned short* __restrict__ g,
                                              int ca, int cb, int half, int moff) {
    int cc = half ? cb : ca;
    return *reinterpret_cast<const unsigned int*>(
        reinterpret_cast<const char*>(g) + (((size_t)cc) << 7) + moff);
}

// ---------------- runtime dtype detection ----------------
// flags[0]: 1 = float inputs are fp32, 0 = bf16
// flags[1]: 1 = edge_index is int64, 0 = int32

__global__ void detect_kernel(const void* __restrict__ x, const void* __restrict__ eidx,
                              int* __restrict__ flags) {
    if (threadIdx.x == 0 && blockIdx.x == 0) {
        const unsigned short* u = (const unsigned short*)x;
        int sane = 0;
        for (int i = 0; i < 64; i++) {
            unsigned short v = u[2 * i];
            int e = (v >> 7) & 0xFF;
            if ((v & 0x7FFF) == 0 || (e >= 90 && e <= 141)) sane++;
        }
        flags[0] = (sane >= 48) ? 0 : 1;
        const int* e32 = (const int*)eidx;
        int nz = 0;
        for (int i = 0; i < 64; i++) if (e32[2 * i + 1] != 0) nz++;
        flags[1] = (nz == 0) ? 1 : 0;
    }
}

// ---------------- segmented-CSR build (key = dst*NSEG + seg) ----

__global__ void key_count(const void* __restrict__ eidx, const int* __restrict__ flags,
                          int* __restrict__ cnt) {
    int e = blockIdx.x * blockDim.x + threadIdx.x;
    if (e < NE) {
        int is64 = flags[1];
        int s = edge_at(eidx, is64, (size_t)e);
        int d = edge_at(eidx, is64, (size_t)NE + e);
        atomicAdd(&cnt[d * NSEG + (s >> SEGSH)], 1);
    }
}

__global__ __launch_bounds__(1024) void scan_reduce(const int* __restrict__ cnt,
                                                    int* __restrict__ bsum) {
    __shared__ int lds[1024];
    int tid = threadIdx.x;
    int i = blockIdx.x * 1024 + tid;
    lds[tid] = (i < NKEY) ? cnt[i] : 0;
    __syncthreads();
    for (int off = 512; off > 0; off >>= 1) {
        if (tid < off) lds[tid] += lds[tid + off];
        __syncthreads();
    }
    if (tid == 0) bsum[blockIdx.x] = lds[0];
}

__global__ __launch_bounds__(1024) void scan_mid(int* __restrict__ bsum, int* __restrict__ total_out) {
    __shared__ int lds[1024];
    __shared__ int base_s;
    int tid = threadIdx.x;
    if (tid == 0) base_s = 0;
    __syncthreads();
    for (int chunk = 0; chunk < KB; chunk += 1024) {
        int i = chunk + tid;
        int v = (i < KB) ? bsum[i] : 0;
        lds[tid] = v;
        __syncthreads();
        for (int off = 1; off < 1024; off <<= 1) {
            int t = (tid >= off) ? lds[tid - off] : 0;
            __syncthreads();
            lds[tid] += t;
            __syncthreads();
        }
        int incl = lds[tid];
        int base = base_s;
        if (i < KB) bsum[i] = base + incl - v;
        __syncthreads();
        if (tid == 1023) base_s = base + incl;
        __syncthreads();
    }
    if (tid == 0) *total_out = base_s;   // == NE
}

__global__ __launch_bounds__(1024) void scan_final(const int* __restrict__ cnt,
                                                   const int* __restrict__ bsum,
                                                   int* __restrict__ keyptr) {
    __shared__ int lds[1024];
    int tid = threadIdx.x;
    int i = blockIdx.x * 1024 + tid;
    int v = (i < NKEY) ? cnt[i] : 0;
    lds[tid] = v;
    __syncthreads();
    for (int off = 1; off < 1024; off <<= 1) {
        int t = (tid >= off) ? lds[tid - off] : 0;
        __syncthreads();
        lds[tid] += t;
        __syncthreads();
    }
    if (i < NKEY) keyptr[i] = bsum[blockIdx.x] + lds[tid] - v;
}

__global__ void dinv_kernel(const int* __restrict__ keyptr, float* __restrict__ dinv) {
    int i = blockIdx.x * blockDim.x + threadIdx.x;
    if (i < NN) {
        int deg = keyptr[(i + 1) * NSEG] - keyptr[i * NSEG];
        dinv[i] = rsqrtf(1.0f + (float)deg);   // +1 self-loop
    }
}

__global__ void scatter_kernel(const void* __restrict__ eidx, const int* __restrict__ flags,
                               const int* __restrict__ keyptr, int* __restrict__ fill,
                               int* __restrict__ col) {
    int e = blockIdx.x * blockDim.x + threadIdx.x;
    if (e < NE) {
        int is64 = flags[1];
        int s = edge_at(eidx, is64, (size_t)e);
        int d = edge_at(eidx, is64, (size_t)NE + e);
        int key = d * NSEG + (s >> SEGSH);
        int pos = keyptr[key] + atomicAdd(&fill[key], 1);
        col[pos] = s;
    }
}

// ---------------- x0 = relu(x @ W1 + b1); x0 bf16, g0 = dinv*x0 bf16 ----------------

__global__ __launch_bounds__(256) void x0_kernel(const void* __restrict__ x,
                                                 const void* __restrict__ W1,
                                                 const void* __restrict__ b1,
                                                 const int* __restrict__ flags,
                                                 const float* __restrict__ dinv,
                                                 unsigned short* __restrict__ x0b,
                                                 unsigned short* __restrict__ g0) {
    __shared__ float lw[FIN * HD];  // 32 KiB
    int isf = flags[0];
    int tid = threadIdx.x;
    for (int i = tid; i < FIN * HD; i += 256) lw[i] = fin_at(W1, isf, i);
    __syncthreads();
    int wave = tid >> 6, lane = tid & 63;
    int row0 = blockIdx.x * RPB + wave * RPW;
    if (row0 >= NN) return;
    unsigned int pa01, pa23, pb01, pb23;
    {
        unsigned short a0 = f2bf(fin_at(x, isf, (size_t)(row0 + 0) * FIN + lane));
        unsigned short a1 = f2bf(fin_at(x, isf, (size_t)(row0 + 1) * FIN + lane));
        unsigned short a2 = f2bf(fin_at(x, isf, (size_t)(row0 + 2) * FIN + lane));
        unsigned short a3 = f2bf(fin_at(x, isf, (size_t)(row0 + 3) * FIN + lane));
        unsigned short c0 = f2bf(fin_at(x, isf, (size_t)(row0 + 0) * FIN + 64 + lane));
        unsigned short c1 = f2bf(fin_at(x, isf, (size_t)(row0 + 1) * FIN + 64 + lane));
        unsigned short c2 = f2bf(fin_at(x, isf, (size_t)(row0 + 2) * FIN + 64 + lane));
        unsigned short c3 = f2bf(fin_at(x, isf, (size_t)(row0 + 3) * FIN + 64 + lane));
        pa01 = ((unsigned int)a0 << 16) | a1;  pa23 = ((unsigned int)a2 << 16) | a3;
        pb01 = ((unsigned int)c0 << 16) | c1;  pb23 = ((unsigned int)c2 << 16) | c3;
    }
    float bias = fin_at(b1, isf, lane);
    float d0 = bias, d1 = bias, d2 = bias, d3 = bias;
    #pragma unroll 8
    for (int k = 0; k < 64; k++) {
        float w = lw[k * HD + lane];
        unsigned int b01 = __shfl(pa01, k, 64);
        unsigned int b23 = __shfl(pa23, k, 64);
        union { unsigned int i; float f; } f0, f1, f2, f3;
        f0.i = b01 & 0xFFFF0000u; f1.i = b01 << 16;
        f2.i = b23 & 0xFFFF0000u; f3.i = b23 << 16;
        d0 += f0.f * w; d1 += f1.f * w; d2 += f2.f * w; d3 += f3.f * w;
    }
    #pragma unroll 8
    for (int k = 0; k < 64; k++) {
        float w = lw[(64 + k) * HD + lane];
        unsigned int b01 = __shfl(pb01, k, 64);
        unsigned int b23 = __shfl(pb23, k, 64);
        union { unsigned int i; float f; } f0, f1, f2, f3;
        f0.i = b01 & 0xFFFF0000u; f1.i = b01 << 16;
        f2.i = b23 & 0xFFFF0000u; f3.i = b23 << 16;
        d0 += f0.f * w; d1 += f1.f * w; d2 += f2.f * w; d3 += f3.f * w;
    }
    float dd[RPW] = {d0, d1, d2, d3};
    #pragma unroll
    for (int r = 0; r < RPW; r++) {
        int row = row0 + r;
        if (row >= NN) continue;
        float v = fmaxf(dd[r], 0.0f);
        x0b[(size_t)row * HD + lane] = f2bf(v);
        g0[(size_t)row * HD + lane] = f2bf(dinv[row] * v);
    }
}

// ---------------- fused layer ----------------
// SEGMENT-MAJOR gather: outer loop over the 13 source segments (8192 nodes =
// 1 MiB of g each), inner loop over the wave's 4 rows. All ~2048 resident
// blocks sweep segments in the same order at statistically equal rates
// (soft lockstep), so the concurrent gather footprint is ~1-2 MiB -> fits
// each XCD's 4 MiB private L2 (vs 12.8 MB random before = L3-bound).
// Pair-gather within a segment (one dword load serves 2 edges); odd tails
// use a masked pair-load (both halves same line -> no extra line traffic).
// p[d] = dinv[d]*(sum g[s] + g[d]); s = .9p + .1x0; h = relu((1-b)s + b s@Wl);
// g_out = dinv*h.

__global__ __launch_bounds__(256, 8) void layer_fused(const int* __restrict__ keyptr,
                                                      const int* __restrict__ col,
                                                      const float* __restrict__ dinv,
                                                      const unsigned short* __restrict__ g_in,
                                                      const unsigned short* __restrict__ x0b,
                                                      unsigned short* __restrict__ g_out,
                                                      const void* __restrict__ convW, int layer,
                                                      const int* __restrict__ flags, float beta) {
    __shared__ float lw[HD * HD];  // 16 KiB
    int isf = flags[0];
    size_t wbase = (size_t)layer * HD * HD;
    int tid = threadIdx.x;
    for (int i = tid; i < HD * HD; i += 256) lw[i] = fin_at(convW, isf, wbase + i);
    __syncthreads();

    // force wave-uniform SGPR value so col/keyptr loads become scalar loads
    int wave = __builtin_amdgcn_readfirstlane(tid >> 6);
    int lane = tid & 63;
    int half = lane >> 5;            // 0: even-edge stream, 1: odd-edge stream
    int moff = (lane & 31) << 2;     // byte offset of this lane's dword in a row
    float mh = half ? 0.0f : 1.0f;   // tail mask: count single edges once

    int row0 = blockIdx.x * RPB + wave * RPW;

    // packed accumulators per row (folded to lane=col layout after the sweep)
    float pe[RPW], po[RPW];
    int jc[RPW];                     // rolling CSR cursor per row (wave-uniform)
    #pragma unroll
    for (int r = 0; r < RPW; r++) {
        pe[r] = 0.0f; po[r] = 0.0f;
        int row = row0 + r;
        jc[r] = (row < NN) ? keyptr[row * NSEG] : 0;
    }

    for (int seg = 0; seg < NSEG; seg++) {
        #pragma unroll
        for (int r = 0; r < RPW; r++) {
            int row = row0 + r;
            if (row >= NN) continue;
            int j = jc[r];
            int end = keyptr[row * NSEG + seg + 1];
            jc[r] = end;
            for (; j + 4 <= end; j += 4) {
                int c0 = col[j + 0], c1 = col[j + 1];
                int c2 = col[j + 2], c3 = col[j + 3];
                unsigned int u0 = gpair(g_in, c0, c1, half, moff);
                unsigned int u1 = gpair(g_in, c2, c3, half, moff);
                pe[r] += bflo(u0); po[r] += bfhi(u0);
                pe[r] += bflo(u1); po[r] += bfhi(u1);
            }
            for (; j + 2 <= end; j += 2) {
                unsigned int u = gpair(g_in, col[j], col[j + 1], half, moff);
                pe[r] += bflo(u); po[r] += bfhi(u);
            }
            if (j < end) {
                int c = col[j];
                unsigned int u = gpair(g_in, c, c, half, moff);
                pe[r] += mh * bflo(u); po[r] += mh * bfhi(u);
            }
        }
    }

    float sacc[RPW];
    float dsc[RPW];
    #pragma unroll
    for (int r = 0; r < RPW; r++) {
        int row = row0 + r;
        if (row >= NN) { sacc[r] = 0.0f; dsc[r] = 1.0f; continue; }
        // fold packed streams back to lane=col layout (once per row)
        float p = pe[r] + __shfl_xor(pe[r], 32, 64);
        float q = po[r] + __shfl_xor(po[r], 32, 64);
        float ge = __shfl(p, lane >> 1, 64);
        float go = __shfl(q, lane >> 1, 64);
        float a = ((lane & 1) ? go : ge) + bf2f(g_in[((size_t)row << 6) + lane]);  // + self-loop
        float di = dinv[row];
        dsc[r] = di;
        sacc[r] = 0.9f * (di * a) + 0.1f * bf2f(x0b[((size_t)row << 6) + lane]);
    }

    // dense: d = s @ Wl ; s packed 2-rows-per-dword bf16, broadcast via shfl
    unsigned int p01 = ((unsigned int)f2bf(sacc[0]) << 16) | f2bf(sacc[1]);
    unsigned int p23 = ((unsigned int)f2bf(sacc[2]) << 16) | f2bf(sacc[3]);
    float d0 = 0.0f, d1 = 0.0f, d2 = 0.0f, d3 = 0.0f;
    #pragma unroll 8
    for (int k = 0; k < 64; k++) {
        float w = lw[k * HD + lane];
        unsigned int b01 = __shfl(p01, k, 64);
        unsigned int b23 = __shfl(p23, k, 64);
        union { unsigned int i; float f; } f0, f1, f2, f3;
        f0.i = b01 & 0xFFFF0000u; f1.i = b01 << 16;
        f2.i = b23 & 0xFFFF0000u; f3.i = b23 << 16;
        d0 += f0.f * w; d1 += f1.f * w;
        d2 += f2.f * w; d3 += f3.f * w;
    }

    float dd[RPW] = {d0, d1, d2, d3};
    float omb = 1.0f - beta;
    #pragma unroll
    for (int r = 0; r < RPW; r++) {
        int row = row0 + r;
        if (row >= NN) continue;
        float res = omb * sacc[r] + beta * dd[r];
        g_out[((size_t)row << 6) + lane] = f2bf(dsc[r] * fmaxf(res, 0.0f));
    }
}

// ---------------- out = log_softmax(h @ W2 + b2), h = g/dinv ----------------

__global__ __launch_bounds__(256) void out_kernel(const unsigned short* __restrict__ g,
                                                  const float* __restrict__ dinv,
                                                  const void* __restrict__ W2,
                                                  const void* __restrict__ b2,
                                                  const int* __restrict__ flags,
                                                  void* __restrict__ out) {
    __shared__ float lw[HD * 64];
    int isf = flags[0];
    int tid = threadIdx.x;
    for (int i = tid; i < HD * 64; i += 256) {
        int k = i >> 6, j = i & 63;
        lw[i] = (j < NC) ? fin_at(W2, isf, (size_t)k * NC + j) : 0.0f;
    }
    __syncthreads();
    int row = blockIdx.x * 4 + (tid >> 6);
    int lane = tid & 63;
    if (row >= NN) return;
    float hv = bf2f(g[(size_t)row * HD + lane]) / dinv[row];
    float acc = (lane < NC) ? fin_at(b2, isf, lane) : 0.0f;
    #pragma unroll 8
    for (int k = 0; k < 64; k++) {
        float hk = __shfl(hv, k, 64);
        acc += hk * lw[k * 64 + lane];
    }
    float mv = (lane < NC) ? acc : -1e30f;
    for (int off = 32; off > 0; off >>= 1) mv = fmaxf(mv, __shfl_xor(mv, off, 64));
    float ex = (lane < NC) ? expf(acc - mv) : 0.0f;
    float se = ex;
    for (int off = 32; off > 0; off >>= 1) se += __shfl_xor(se, off, 64);
    float res = acc - mv - logf(se);
    if (lane < NC) {
        size_t oi = (size_t)row * NC + lane;
        if (isf) ((float*)out)[oi] = res;
        else     ((__hip_bfloat16*)out)[oi] = __float2bfloat16(res);
    }
}

// ---------------- host ----------------

static inline size_t align256(size_t x) { return (x + 255) & ~(size_t)255; }

extern "C" void kernel_launch(void* const* d_in, const int* in_sizes, int n_in,
                              void* d_out, int out_size, void* d_ws, size_t ws_size,
                              hipStream_t stream) {
    const void* x     = d_in[0];
    const void* eidx  = d_in[1];
    const void* W1    = d_in[2];
    const void* b1    = d_in[3];
    const void* convW = d_in[4];
    const void* W2    = d_in[5];
    const void* b2    = d_in[6];

    char* p = (char*)d_ws;
    size_t off = 0;
    auto alloc = [&](size_t bytes) { void* r = p + off; off += align256(bytes); return r; };
    int*            flags   = (int*)alloc(256);
    int*            cnt     = (int*)alloc((size_t)NKEY * 4);
    int*            fill    = (int*)alloc((size_t)NKEY * 4);
    int*            keyptr  = (int*)alloc((size_t)(NKEY + 1) * 4);
    int*            bsum    = (int*)alloc((size_t)KB * 4);
    float*          dinv    = (float*)alloc((size_t)NN * 4);
    int*            col     = (int*)alloc((size_t)NE * 4);
    unsigned short* x0b     = (unsigned short*)alloc((size_t)NN * HD * 2);
    unsigned short* hA      = (unsigned short*)alloc((size_t)NN * HD * 2);
    unsigned short* hB      = (unsigned short*)alloc((size_t)NN * HD * 2);

    detect_kernel<<<1, 64, 0, stream>>>(x, eidx, flags);

    hipMemsetAsync(cnt, 0, (size_t)NKEY * 4, stream);
    hipMemsetAsync(fill, 0, (size_t)NKEY * 4, stream);
    key_count<<<(NE + 255) / 256, 256, 0, stream>>>(eidx, flags, cnt);
    scan_reduce<<<KB, 1024, 0, stream>>>(cnt, bsum);
    scan_mid<<<1, 1024, 0, stream>>>(bsum, keyptr + NKEY);
    scan_final<<<KB, 1024, 0, stream>>>(cnt, bsum, keyptr);
    dinv_kernel<<<(NN + 255) / 256, 256, 0, stream>>>(keyptr, dinv);
    scatter_kernel<<<(NE + 255) / 256, 256, 0, stream>>>(eidx, flags, keyptr, fill, col);

    int fb = (NN + RPB - 1) / RPB;  // 6250 blocks
    x0_kernel<<<fb, 256, 0, stream>>>(x, W1, b1, flags, dinv, x0b, hA);

    unsigned short* gin = hA;
    unsigned short* gout = hB;
    for (int l = 0; l < NL; l++) {
        float beta = logf(0.5f / (float)(l + 1) + 1.0f);
        layer_fused<<<fb, 256, 0, stream>>>(keyptr, col, dinv, gin, x0b, gout,
                                            convW, l, flags, beta);
        unsigned short* t = gin; gin = gout; gout = t;
    }
    out_kernel<<<(NN + 3) / 4, 256, 0, stream>>>(gin, dinv, W2, b2, flags, (void*)d_out);
}

// Round 3
// 6607.031 us; speedup vs baseline: 1.8619x; 1.8619x over previous
//
#include <hip/hip_runtime.h>
#include <hip/hip_bf16.h>
#include <math.h>

#define NN 100000
#define NE 3200000
#define FIN 128
#define HD 64
#define NL 64
#define NC 47
#define RPW 4               // rows per wave
#define WPB 4               // waves per block
#define RPB (RPW * WPB)     // rows per block = 16

#define SEGSH 13            // source segment = 8192 nodes (kept for CSR build)
#define NSEG 13             // ceil(100000 / 8192)
#define NKEY (NN * NSEG)    // 1.3M (dst, seg) keys
#define KB ((NKEY + 1023) / 1024)   // scan blocks

// ---------------- helpers ----------------

__device__ __forceinline__ float bf2f(unsigned short u) {
    union { unsigned int i; float f; } v; v.i = ((unsigned int)u) << 16; return v.f;
}
__device__ __forceinline__ unsigned short f2bf(float f) {
    __hip_bfloat16 h = __float2bfloat16(f);   // RNE
    return *reinterpret_cast<unsigned short*>(&h);
}
__device__ __forceinline__ float bflo(unsigned int u) {
    union { unsigned int i; float f; } v; v.i = u << 16; return v.f;
}
__device__ __forceinline__ float bfhi(unsigned int u) {
    union { unsigned int i; float f; } v; v.i = u & 0xFFFF0000u; return v.f;
}
__device__ __forceinline__ float fin_at(const void* p, int isf32, size_t i) {
    return isf32 ? ((const float*)p)[i]
                 : __bfloat162float(((const __hip_bfloat16*)p)[i]);
}
__device__ __forceinline__ int edge_at(const void* p, int is64, size_t i) {
    return is64 ? (int)((const long long*)p)[i] : ((const int*)p)[i];
}

// ---------------- runtime dtype detection ----------------
// flags[0]: 1 = float inputs are fp32, 0 = bf16
// flags[1]: 1 = edge_index is int64, 0 = int32

__global__ void detect_kernel(const void* __restrict__ x, const void* __restrict__ eidx,
                              int* __restrict__ flags) {
    if (threadIdx.x == 0 && blockIdx.x == 0) {
        const unsigned short* u = (const unsigned short*)x;
        int sane = 0;
        for (int i = 0; i < 64; i++) {
            unsigned short v = u[2 * i];
            int e = (v >> 7) & 0xFF;
            if ((v & 0x7FFF) == 0 || (e >= 90 && e <= 141)) sane++;
        }
        flags[0] = (sane >= 48) ? 0 : 1;
        const int* e32 = (const int*)eidx;
        int nz = 0;
        for (int i = 0; i < 64; i++) if (e32[2 * i + 1] != 0) nz++;
        flags[1] = (nz == 0) ? 1 : 0;
    }
}

// ---------------- segmented-CSR build (key = dst*NSEG + seg) ----

__global__ void key_count(const void* __restrict__ eidx, const int* __restrict__ flags,
                          int* __restrict__ cnt) {
    int e = blockIdx.x * blockDim.x + threadIdx.x;
    if (e < NE) {
        int is64 = flags[1];
        int s = edge_at(eidx, is64, (size_t)e);
        int d = edge_at(eidx, is64, (size_t)NE + e);
        atomicAdd(&cnt[d * NSEG + (s >> SEGSH)], 1);
    }
}

__global__ __launch_bounds__(1024) void scan_reduce(const int* __restrict__ cnt,
                                                    int* __restrict__ bsum) {
    __shared__ int lds[1024];
    int tid = threadIdx.x;
    int i = blockIdx.x * 1024 + tid;
    lds[tid] = (i < NKEY) ? cnt[i] : 0;
    __syncthreads();
    for (int off = 512; off > 0; off >>= 1) {
        if (tid < off) lds[tid] += lds[tid + off];
        __syncthreads();
    }
    if (tid == 0) bsum[blockIdx.x] = lds[0];
}

__global__ __launch_bounds__(1024) void scan_mid(int* __restrict__ bsum, int* __restrict__ total_out) {
    __shared__ int lds[1024];
    __shared__ int base_s;
    int tid = threadIdx.x;
    if (tid == 0) base_s = 0;
    __syncthreads();
    for (int chunk = 0; chunk < KB; chunk += 1024) {
        int i = chunk + tid;
        int v = (i < KB) ? bsum[i] : 0;
        lds[tid] = v;
        __syncthreads();
        for (int off = 1; off < 1024; off <<= 1) {
            int t = (tid >= off) ? lds[tid - off] : 0;
            __syncthreads();
            lds[tid] += t;
            __syncthreads();
        }
        int incl = lds[tid];
        int base = base_s;
        if (i < KB) bsum[i] = base + incl - v;
        __syncthreads();
        if (tid == 1023) base_s = base + incl;
        __syncthreads();
    }
    if (tid == 0) *total_out = base_s;   // == NE
}

__global__ __launch_bounds__(1024) void scan_final(const int* __restrict__ cnt,
                                                   const int* __restrict__ bsum,
                                                   int* __restrict__ keyptr) {
    __shared__ int lds[1024];
    int tid = threadIdx.x;
    int i = blockIdx.x * 1024 + tid;
    int v = (i < NKEY) ? cnt[i] : 0;
    lds[tid] = v;
    __syncthreads();
    for (int off = 1; off < 1024; off <<= 1) {
        int t = (tid >= off) ? lds[tid - off] : 0;
        __syncthreads();
        lds[tid] += t;
        __syncthreads();
    }
    if (i < NKEY) keyptr[i] = bsum[blockIdx.x] + lds[tid] - v;
}

__global__ void dinv_kernel(const int* __restrict__ keyptr, float* __restrict__ dinv) {
    int i = blockIdx.x * blockDim.x + threadIdx.x;
    if (i < NN) {
        int deg = keyptr[(i + 1) * NSEG] - keyptr[i * NSEG];
        dinv[i] = rsqrtf(1.0f + (float)deg);   // +1 self-loop
    }
}

__global__ void scatter_kernel(const void* __restrict__ eidx, const int* __restrict__ flags,
                               const int* __restrict__ keyptr, int* __restrict__ fill,
                               int* __restrict__ col) {
    int e = blockIdx.x * blockDim.x + threadIdx.x;
    if (e < NE) {
        int is64 = flags[1];
        int s = edge_at(eidx, is64, (size_t)e);
        int d = edge_at(eidx, is64, (size_t)NE + e);
        int key = d * NSEG + (s >> SEGSH);
        int pos = keyptr[key] + atomicAdd(&fill[key], 1);
        col[pos] = s;
    }
}

// ---------------- x0 = relu(x @ W1 + b1); x0 bf16, g0 = dinv*x0 bf16 ----------------

__global__ __launch_bounds__(256) void x0_kernel(const void* __restrict__ x,
                                                 const void* __restrict__ W1,
                                                 const void* __restrict__ b1,
                                                 const int* __restrict__ flags,
                                                 const float* __restrict__ dinv,
                                                 unsigned short* __restrict__ x0b,
                                                 unsigned short* __restrict__ g0) {
    __shared__ float lw[FIN * HD];  // 32 KiB
    int isf = flags[0];
    int tid = threadIdx.x;
    for (int i = tid; i < FIN * HD; i += 256) lw[i] = fin_at(W1, isf, i);
    __syncthreads();
    int wave = tid >> 6, lane = tid & 63;
    int row0 = blockIdx.x * RPB + wave * RPW;
    if (row0 >= NN) return;
    unsigned int pa01, pa23, pb01, pb23;
    {
        unsigned short a0 = f2bf(fin_at(x, isf, (size_t)(row0 + 0) * FIN + lane));
        unsigned short a1 = f2bf(fin_at(x, isf, (size_t)(row0 + 1) * FIN + lane));
        unsigned short a2 = f2bf(fin_at(x, isf, (size_t)(row0 + 2) * FIN + lane));
        unsigned short a3 = f2bf(fin_at(x, isf, (size_t)(row0 + 3) * FIN + lane));
        unsigned short c0 = f2bf(fin_at(x, isf, (size_t)(row0 + 0) * FIN + 64 + lane));
        unsigned short c1 = f2bf(fin_at(x, isf, (size_t)(row0 + 1) * FIN + 64 + lane));
        unsigned short c2 = f2bf(fin_at(x, isf, (size_t)(row0 + 2) * FIN + 64 + lane));
        unsigned short c3 = f2bf(fin_at(x, isf, (size_t)(row0 + 3) * FIN + 64 + lane));
        pa01 = ((unsigned int)a0 << 16) | a1;  pa23 = ((unsigned int)a2 << 16) | a3;
        pb01 = ((unsigned int)c0 << 16) | c1;  pb23 = ((unsigned int)c2 << 16) | c3;
    }
    float bias = fin_at(b1, isf, lane);
    float d0 = bias, d1 = bias, d2 = bias, d3 = bias;
    #pragma unroll 8
    for (int k = 0; k < 64; k++) {
        float w = lw[k * HD + lane];
        unsigned int b01 = __shfl(pa01, k, 64);
        unsigned int b23 = __shfl(pa23, k, 64);
        union { unsigned int i; float f; } f0, f1, f2, f3;
        f0.i = b01 & 0xFFFF0000u; f1.i = b01 << 16;
        f2.i = b23 & 0xFFFF0000u; f3.i = b23 << 16;
        d0 += f0.f * w; d1 += f1.f * w; d2 += f2.f * w; d3 += f3.f * w;
    }
    #pragma unroll 8
    for (int k = 0; k < 64; k++) {
        float w = lw[(64 + k) * HD + lane];
        unsigned int b01 = __shfl(pb01, k, 64);
        unsigned int b23 = __shfl(pb23, k, 64);
        union { unsigned int i; float f; } f0, f1, f2, f3;
        f0.i = b01 & 0xFFFF0000u; f1.i = b01 << 16;
        f2.i = b23 & 0xFFFF0000u; f3.i = b23 << 16;
        d0 += f0.f * w; d1 += f1.f * w; d2 += f2.f * w; d3 += f3.f * w;
    }
    float dd[RPW] = {d0, d1, d2, d3};
    #pragma unroll
    for (int r = 0; r < RPW; r++) {
        int row = row0 + r;
        if (row >= NN) continue;
        float v = fmaxf(dd[r], 0.0f);
        x0b[(size_t)row * HD + lane] = f2bf(v);
        g0[(size_t)row * HD + lane] = f2bf(dinv[row] * v);
    }
}

// ---------------- fused layer ----------------
// Wide-MLP gather: 8 lanes per edge row x dwordx4 (16 B/lane) -> ONE vector
// load fetches 8 full 128-B edge rows; 4 such loads per chunk = 32 edges in
// flight per wave (4x the previous pair-gather MLP; the gather is
// latency-bound, proven by round-2's MLP-collapse regression).
// Edge indices via per-lane vector load col[j + 8g + (lane>>3)] (coalesced
// 32-B broadcast). Tails are branchless: index clamp + fmaf mask.
// Accumulators are slice-packed (8 cols/lane); folded to lane=col once per
// row via 3x shfl_xor reduce + 8 shfl + 7-cndmask select.
// p[d] = dinv[d]*(sum g[s] + g[d]); s = .9p + .1x0; h = relu((1-b)s + b s@Wl);
// g_out = dinv*h.

__global__ __launch_bounds__(256, 8) void layer_fused(const int* __restrict__ keyptr,
                                                      const int* __restrict__ col,
                                                      const float* __restrict__ dinv,
                                                      const unsigned short* __restrict__ g_in,
                                                      const unsigned short* __restrict__ x0b,
                                                      unsigned short* __restrict__ g_out,
                                                      const void* __restrict__ convW, int layer,
                                                      const int* __restrict__ flags, float beta) {
    __shared__ float lw[HD * HD];  // 16 KiB
    int isf = flags[0];
    size_t wbase = (size_t)layer * HD * HD;
    int tid = threadIdx.x;
    for (int i = tid; i < HD * HD; i += 256) lw[i] = fin_at(convW, isf, wbase + i);
    __syncthreads();

    // force wave-uniform SGPR value so keyptr loads become scalar loads
    int wave = __builtin_amdgcn_readfirstlane(tid >> 6);
    int lane = tid & 63;
    int eslot = lane >> 3;            // edge slot 0..7 within a group
    int sbyte = (lane & 7) << 4;      // byte offset of this lane's 16-B slice
    const char* gb = (const char*)g_in;

    int row0 = blockIdx.x * RPB + wave * RPW;

    float sacc[RPW];
    float dsc[RPW];
    #pragma unroll
    for (int r = 0; r < RPW; r++) {
        int row = row0 + r;
        if (row >= NN) { sacc[r] = 0.0f; dsc[r] = 1.0f; continue; }
        int start = keyptr[row * NSEG];
        int end   = keyptr[(row + 1) * NSEG];

        float a0 = 0.0f, a1 = 0.0f, a2 = 0.0f, a3 = 0.0f;
        float a4 = 0.0f, a5 = 0.0f, a6 = 0.0f, a7 = 0.0f;

        for (int j = start; j < end; j += 32) {
            int le = end - 1;
            int i0 = j + eslot, i1 = i0 + 8, i2 = i0 + 16, i3 = i0 + 24;
            int c0 = col[i0 < end ? i0 : le];
            int c1 = col[i1 < end ? i1 : le];
            int c2 = col[i2 < end ? i2 : le];
            int c3 = col[i3 < end ? i3 : le];
            uint4 u0 = *reinterpret_cast<const uint4*>(gb + (((size_t)c0) << 7) + sbyte);
            uint4 u1 = *reinterpret_cast<const uint4*>(gb + (((size_t)c1) << 7) + sbyte);
            uint4 u2 = *reinterpret_cast<const uint4*>(gb + (((size_t)c2) << 7) + sbyte);
            uint4 u3 = *reinterpret_cast<const uint4*>(gb + (((size_t)c3) << 7) + sbyte);
            float m0 = (i0 < end) ? 1.0f : 0.0f;
            float m1 = (i1 < end) ? 1.0f : 0.0f;
            float m2 = (i2 < end) ? 1.0f : 0.0f;
            float m3 = (i3 < end) ? 1.0f : 0.0f;
            a0 = fmaf(m0, bflo(u0.x), a0); a1 = fmaf(m0, bfhi(u0.x), a1);
            a2 = fmaf(m0, bflo(u0.y), a2); a3 = fmaf(m0, bfhi(u0.y), a3);
            a4 = fmaf(m0, bflo(u0.z), a4); a5 = fmaf(m0, bfhi(u0.z), a5);
            a6 = fmaf(m0, bflo(u0.w), a6); a7 = fmaf(m0, bfhi(u0.w), a7);
            a0 = fmaf(m1, bflo(u1.x), a0); a1 = fmaf(m1, bfhi(u1.x), a1);
            a2 = fmaf(m1, bflo(u1.y), a2); a3 = fmaf(m1, bfhi(u1.y), a3);
            a4 = fmaf(m1, bflo(u1.z), a4); a5 = fmaf(m1, bfhi(u1.z), a5);
            a6 = fmaf(m1, bflo(u1.w), a6); a7 = fmaf(m1, bfhi(u1.w), a7);
            a0 = fmaf(m2, bflo(u2.x), a0); a1 = fmaf(m2, bfhi(u2.x), a1);
            a2 = fmaf(m2, bflo(u2.y), a2); a3 = fmaf(m2, bfhi(u2.y), a3);
            a4 = fmaf(m2, bflo(u2.z), a4); a5 = fmaf(m2, bfhi(u2.z), a5);
            a6 = fmaf(m2, bflo(u2.w), a6); a7 = fmaf(m2, bfhi(u2.w), a7);
            a0 = fmaf(m3, bflo(u3.x), a0); a1 = fmaf(m3, bfhi(u3.x), a1);
            a2 = fmaf(m3, bflo(u3.y), a2); a3 = fmaf(m3, bfhi(u3.y), a3);
            a4 = fmaf(m3, bflo(u3.z), a4); a5 = fmaf(m3, bfhi(u3.z), a5);
            a6 = fmaf(m3, bflo(u3.w), a6); a7 = fmaf(m3, bfhi(u3.w), a7);
        }

        // reduce across the 8 edge-slot classes (lanes differing in bits 3..5)
        a0 += __shfl_xor(a0, 8, 64); a0 += __shfl_xor(a0, 16, 64); a0 += __shfl_xor(a0, 32, 64);
        a1 += __shfl_xor(a1, 8, 64); a1 += __shfl_xor(a1, 16, 64); a1 += __shfl_xor(a1, 32, 64);
        a2 += __shfl_xor(a2, 8, 64); a2 += __shfl_xor(a2, 16, 64); a2 += __shfl_xor(a2, 32, 64);
        a3 += __shfl_xor(a3, 8, 64); a3 += __shfl_xor(a3, 16, 64); a3 += __shfl_xor(a3, 32, 64);
        a4 += __shfl_xor(a4, 8, 64); a4 += __shfl_xor(a4, 16, 64); a4 += __shfl_xor(a4, 32, 64);
        a5 += __shfl_xor(a5, 8, 64); a5 += __shfl_xor(a5, 16, 64); a5 += __shfl_xor(a5, 32, 64);
        a6 += __shfl_xor(a6, 8, 64); a6 += __shfl_xor(a6, 16, 64); a6 += __shfl_xor(a6, 32, 64);
        a7 += __shfl_xor(a7, 8, 64); a7 += __shfl_xor(a7, 16, 64); a7 += __shfl_xor(a7, 32, 64);

        // redistribute: lane c takes acc[c&7] from lane (c>>3)
        int srcl = lane >> 3;
        float t0 = __shfl(a0, srcl, 64);
        float t1 = __shfl(a1, srcl, 64);
        float t2 = __shfl(a2, srcl, 64);
        float t3 = __shfl(a3, srcl, 64);
        float t4 = __shfl(a4, srcl, 64);
        float t5 = __shfl(a5, srcl, 64);
        float t6 = __shfl(a6, srcl, 64);
        float t7 = __shfl(a7, srcl, 64);
        int b0 = lane & 1, b1 = (lane >> 1) & 1, b2 = (lane >> 2) & 1;
        float s01 = b0 ? t1 : t0, s23 = b0 ? t3 : t2;
        float s45 = b0 ? t5 : t4, s67 = b0 ? t7 : t6;
        float sA = b1 ? s23 : s01, sB = b1 ? s67 : s45;
        float gsum = b2 ? sB : sA;

        float a = gsum + bf2f(g_in[((size_t)row << 6) + lane]);  // + self-loop
        float di = dinv[row];
        dsc[r] = di;
        sacc[r] = 0.9f * (di * a) + 0.1f * bf2f(x0b[((size_t)row << 6) + lane]);
    }

    // dense: d = s @ Wl ; s packed 2-rows-per-dword bf16, broadcast via shfl
    unsigned int p01 = ((unsigned int)f2bf(sacc[0]) << 16) | f2bf(sacc[1]);
    unsigned int p23 = ((unsigned int)f2bf(sacc[2]) << 16) | f2bf(sacc[3]);
    float d0 = 0.0f, d1 = 0.0f, d2 = 0.0f, d3 = 0.0f;
    #pragma unroll 8
    for (int k = 0; k < 64; k++) {
        float w = lw[k * HD + lane];
        unsigned int b01 = __shfl(p01, k, 64);
        unsigned int b23 = __shfl(p23, k, 64);
        union { unsigned int i; float f; } f0, f1, f2, f3;
        f0.i = b01 & 0xFFFF0000u; f1.i = b01 << 16;
        f2.i = b23 & 0xFFFF0000u; f3.i = b23 << 16;
        d0 += f0.f * w; d1 += f1.f * w;
        d2 += f2.f * w; d3 += f3.f * w;
    }

    float dd[RPW] = {d0, d1, d2, d3};
    float omb = 1.0f - beta;
    #pragma unroll
    for (int r = 0; r < RPW; r++) {
        int row = row0 + r;
        if (row >= NN) continue;
        float res = omb * sacc[r] + beta * dd[r];
        g_out[((size_t)row << 6) + lane] = f2bf(dsc[r] * fmaxf(res, 0.0f));
    }
}

// ---------------- out = log_softmax(h @ W2 + b2), h = g/dinv ----------------

__global__ __launch_bounds__(256) void out_kernel(const unsigned short* __restrict__ g,
                                                  const float* __restrict__ dinv,
                                                  const void* __restrict__ W2,
                                                  const void* __restrict__ b2,
                                                  const int* __restrict__ flags,
                                                  void* __restrict__ out) {
    __shared__ float lw[HD * 64];
    int isf = flags[0];
    int tid = threadIdx.x;
    for (int i = tid; i < HD * 64; i += 256) {
        int k = i >> 6, j = i & 63;
        lw[i] = (j < NC) ? fin_at(W2, isf, (size_t)k * NC + j) : 0.0f;
    }
    __syncthreads();
    int row = blockIdx.x * 4 + (tid >> 6);
    int lane = tid & 63;
    if (row >= NN) return;
    float hv = bf2f(g[(size_t)row * HD + lane]) / dinv[row];
    float acc = (lane < NC) ? fin_at(b2, isf, lane) : 0.0f;
    #pragma unroll 8
    for (int k = 0; k < 64; k++) {
        float hk = __shfl(hv, k, 64);
        acc += hk * lw[k * 64 + lane];
    }
    float mv = (lane < NC) ? acc : -1e30f;
    for (int off = 32; off > 0; off >>= 1) mv = fmaxf(mv, __shfl_xor(mv, off, 64));
    float ex = (lane < NC) ? expf(acc - mv) : 0.0f;
    float se = ex;
    for (int off = 32; off > 0; off >>= 1) se += __shfl_xor(se, off, 64);
    float res = acc - mv - logf(se);
    if (lane < NC) {
        size_t oi = (size_t)row * NC + lane;
        if (isf) ((float*)out)[oi] = res;
        else     ((__hip_bfloat16*)out)[oi] = __float2bfloat16(res);
    }
}

// ---------------- host ----------------

static inline size_t align256(size_t x) { return (x + 255) & ~(size_t)255; }

extern "C" void kernel_launch(void* const* d_in, const int* in_sizes, int n_in,
                              void* d_out, int out_size, void* d_ws, size_t ws_size,
                              hipStream_t stream) {
    const void* x     = d_in[0];
    const void* eidx  = d_in[1];
    const void* W1    = d_in[2];
    const void* b1    = d_in[3];
    const void* convW = d_in[4];
    const void* W2    = d_in[5];
    const void* b2    = d_in[6];

    char* p = (char*)d_ws;
    size_t off = 0;
    auto alloc = [&](size_t bytes) { void* r = p + off; off += align256(bytes); return r; };
    int*            flags   = (int*)alloc(256);
    int*            cnt     = (int*)alloc((size_t)NKEY * 4);
    int*            fill    = (int*)alloc((size_t)NKEY * 4);
    int*            keyptr  = (int*)alloc((size_t)(NKEY + 1) * 4);
    int*            bsum    = (int*)alloc((size_t)KB * 4);
    float*          dinv    = (float*)alloc((size_t)NN * 4);
    int*            col     = (int*)alloc((size_t)NE * 4);
    unsigned short* x0b     = (unsigned short*)alloc((size_t)NN * HD * 2);
    unsigned short* hA      = (unsigned short*)alloc((size_t)NN * HD * 2);
    unsigned short* hB      = (unsigned short*)alloc((size_t)NN * HD * 2);

    detect_kernel<<<1, 64, 0, stream>>>(x, eidx, flags);

    hipMemsetAsync(cnt, 0, (size_t)NKEY * 4, stream);
    hipMemsetAsync(fill, 0, (size_t)NKEY * 4, stream);
    key_count<<<(NE + 255) / 256, 256, 0, stream>>>(eidx, flags, cnt);
    scan_reduce<<<KB, 1024, 0, stream>>>(cnt, bsum);
    scan_mid<<<1, 1024, 0, stream>>>(bsum, keyptr + NKEY);
    scan_final<<<KB, 1024, 0, stream>>>(cnt, bsum, keyptr);
    dinv_kernel<<<(NN + 255) / 256, 256, 0, stream>>>(keyptr, dinv);
    scatter_kernel<<<(NE + 255) / 256, 256, 0, stream>>>(eidx, flags, keyptr, fill, col);

    int fb = (NN + RPB - 1) / RPB;  // 6250 blocks
    x0_kernel<<<fb, 256, 0, stream>>>(x, W1, b1, flags, dinv, x0b, hA);

    unsigned short* gin = hA;
    unsigned short* gout = hB;
    for (int l = 0; l < NL; l++) {
        float beta = logf(0.5f / (float)(l + 1) + 1.0f);
        layer_fused<<<fb, 256, 0, stream>>>(keyptr, col, dinv, gin, x0b, gout,
                                            convW, l, flags, beta);
        unsigned short* t = gin; gin = gout; gout = t;
    }
    out_kernel<<<(NN + 3) / 4, 256, 0, stream>>>(gin, dinv, W2, b2, flags, (void*)d_out);
}